// Round 10
// baseline (286.677 us; speedup 1.0000x reference)
//
#include <hip/hip_runtime.h>

typedef unsigned short ushort_t;
typedef __attribute__((ext_vector_type(8))) short bf16x8;
typedef __attribute__((ext_vector_type(4))) float f32x4;
typedef __attribute__((ext_vector_type(8))) unsigned short ushort8;

// Problem geometry (compile-time)
constexpr int BB   = 8;
constexpr int CC   = 256;
constexpr int OUTC = 256;
constexpr int KK   = 7;
constexpr int LL   = 2048;
constexpr int PADc = 3;
constexpr int KD   = CC * KK;        // 1792 reduction dim
constexpr int MOFF = CC * KK * 2;    // 3584 offset-conv out channels
constexpr int NTOT = BB * LL;        // 16384
constexpr int NKSTEPS = KD / 32;     // 56 (BK=32, for gemm128_out)
constexpr int NT64 = KD / 64;        // 28 BK=64 tiles
constexpr int NITER = NT64 / 2;      // 14 iterations (2 tiles each)
constexpr int LP   = LL + 6;         // 2054 padded length

__device__ __forceinline__ ushort_t f2bf(float f) {
    unsigned u = __float_as_uint(f);
    unsigned r = (u + 0x7fffu + ((u >> 16) & 1u)) >> 16;  // RNE
    return (ushort_t)r;
}

// -------------------- cast f32 -> bf16 (vectorized, main-conv weight) --------------------
__global__ __launch_bounds__(256) void cast_k(const float4* __restrict__ src,
                                              ushort_t* __restrict__ dst, int n4) {
    int i = blockIdx.x * 256 + threadIdx.x;
    if (i >= n4) return;
    float4 v = src[i];
    ushort4 o;
    o.x = f2bf(v.x); o.y = f2bf(v.y); o.z = f2bf(v.z); o.w = f2bf(v.w);
    *(ushort4*)(dst + (size_t)i * 4) = o;
}

// ------ cast + permute w_off into c-major/tap-inner K layout ------
// K index q: chunk ks = q>>5 (cs = ks/7, tap = ks%7), cl = q&31 -> (c = cs*32+cl, kk = tap)
__global__ __launch_bounds__(256) void castperm_woff(const float* __restrict__ src,
                                                     ushort_t* __restrict__ dst) {
    int i = blockIdx.x * 256 + threadIdx.x;
    if (i >= MOFF * KD) return;
    int dr  = i / KD;
    int q   = i - dr * KD;
    int cs   = q / 224;
    int r224 = q - cs * 224;
    int tap  = r224 >> 5;
    int cl   = r224 & 31;
    int c = cs * 32 + cl;
    int r = (dr & 1) ? (KD + (dr >> 1)) : (dr >> 1);
    dst[i] = f2bf(src[(r * 256 + c) * 7 + tap]);
}

// -------------------- padded transpose: xp[b][l+3][c] = x[b][c][l] --------------------
__global__ __launch_bounds__(256) void xpose_k(const float* __restrict__ x,
                                               ushort_t* __restrict__ xp) {
    __shared__ float tile[32][257];
    int bid = blockIdx.x;                 // 8 b x 8 ltiles x 8 cchunks = 512
    int b  = bid >> 6;
    int l0 = ((bid >> 3) & 7) * 256;
    int c0 = (bid & 7) * 32;
    int tid = threadIdx.x;
    const float* xb = x + (size_t)b * (CC * LL);
    ushort_t* xpb = xp + (size_t)b * (LP * 256);
#pragma unroll 4
    for (int k = 0; k < 32; ++k)
        tile[k][tid] = xb[(size_t)(c0 + k) * LL + l0 + tid];
    __syncthreads();
    int lp = l0 + tid + 3;
#pragma unroll
    for (int q = 0; q < 8; ++q) {
        ushort4 v;
        v.x = f2bf(tile[4 * q + 0][tid]);
        v.y = f2bf(tile[4 * q + 1][tid]);
        v.z = f2bf(tile[4 * q + 2][tid]);
        v.w = f2bf(tile[4 * q + 3][tid]);
        *(ushort4*)(xpb + (size_t)lp * 256 + c0 + 4 * q) = v;
    }
    if ((bid & 63) == 0) {
#pragma unroll
        for (int r = 0; r < 6; ++r) {
            int glp = (r < 3) ? r : (2048 + r);
            xpb[glp * 256 + tid] = 0;
        }
    }
}

// -------------------- async global->LDS 16B --------------------
__device__ __forceinline__ void load_lds16(const ushort_t* g, ushort_t* l) {
    __builtin_amdgcn_global_load_lds(
        (const __attribute__((address_space(1))) unsigned int*)g,
        (__attribute__((address_space(3))) unsigned int*)l, 16, 0, 0);
}

// ==================== 256x256 8-phase counted-vmcnt GEMM (BK=64) + fused sampling ====================
// dbuf d (d=0 even tiles, 1 odd): A at d*32768 (256 rows x 64 K), B at d*32768+16384.
// Halves: Ah = +h*8192, Bh = +16384+h*8192 (128 rows x 128B each; 2 gload_lds/lane).
// LDS row layout: row r: 8 slots of 16B, slot swizzle u_store = slot ^ (r&7) (via
// pre-swizzled global source; read side u = (q*4+kh) ^ (r15&7)).
// 8 waves 2Mx4N, per-wave 128x64, acc[8][4]. Per iteration (2 K-tiles, 8 phases):
//  ph1..4 = quadrants (r0c0, r0c1, r1c0, r1c1) of tile t0 (dbuf0), ds_reads 12/4/8/0;
//  ph5..8 = same for t1 (dbuf1). Stage 1 half per phase (order in launch comment),
//  vmcnt(4) only at ph4/ph8: steady state 12 outstanding -> 4; gate+barrier proves
//  the next tile's 4 halves landed before any wave reads them.
__device__ __forceinline__ void stageA8(ushort_t* dsthalf, const ushort_t* __restrict__ A,
                                        int m0, int h, int tile, int wid, int lane) {
    int gs = (lane & 7) ^ ((lane >> 3) & 7);
#pragma unroll
    for (int j = 0; j < 2; ++j) {
        int rl = (wid * 2 + j) * 8 + (lane >> 3);     // 0..127 within half
        load_lds16(A + (size_t)(m0 + h * 128 + rl) * KD + tile * 64 + gs * 8,
                   dsthalf + (wid * 2 + j) * 512);
    }
}
__device__ __forceinline__ void stageB8(ushort_t* dsthalf, const ushort_t* __restrict__ xp,
                                        int n0, int h, int tile, int wid, int lane) {
    int gs = (lane & 7) ^ ((lane >> 3) & 7);
    int ks = tile * 2 + (gs >> 2);                    // 32-chunk index, c-major map
    int cs = ks / 7, tap = ks - cs * 7;
    const ushort_t* base = xp + (size_t)(n0 >> 11) * (LP * 256)
                         + (size_t)((n0 & 2047) + h * 128 + tap) * 256 + cs * 32 + (gs & 3) * 8;
#pragma unroll
    for (int j = 0; j < 2; ++j) {
        int rl = (wid * 2 + j) * 8 + (lane >> 3);
        load_lds16(base + (size_t)rl * 256, dsthalf + (wid * 2 + j) * 512);
    }
}

__device__ __forceinline__ void rdA(bf16x8 (&af)[4][2], const ushort_t* dA,
                                    int rbase, int r15, int kh) {
#pragma unroll
    for (int f = 0; f < 4; ++f)
#pragma unroll
        for (int q = 0; q < 2; ++q) {
            int row = rbase + f * 16 + r15;
            af[f][q] = *(const bf16x8*)(dA + row * 64 + ((q * 4 + kh) ^ (r15 & 7)) * 8);
        }
}
__device__ __forceinline__ void rdB(bf16x8 (&bq)[4][2], int c0f, const ushort_t* dB,
                                    int cbase, int r15, int kh) {
#pragma unroll
    for (int f = 0; f < 2; ++f)
#pragma unroll
        for (int q = 0; q < 2; ++q) {
            int row = cbase + f * 16 + r15;
            bq[c0f + f][q] = *(const bf16x8*)(dB + row * 64 + ((q * 4 + kh) ^ (r15 & 7)) * 8);
        }
}

template <int I0, int J0>
__device__ __forceinline__ void mfmaQ(f32x4 (&acc)[8][4], const bf16x8 (&af)[4][2],
                                      const bf16x8 (&bq)[4][2]) {
    __builtin_amdgcn_s_setprio(1);
#pragma unroll
    for (int i = 0; i < 4; ++i)
#pragma unroll
        for (int j = 0; j < 2; ++j)
#pragma unroll
            for (int q = 0; q < 2; ++q)
                acc[I0 + i][J0 + j] = __builtin_amdgcn_mfma_f32_16x16x32_bf16(
                    af[i][q], bq[J0 + j][q], acc[I0 + i][J0 + j], 0, 0, 0);
    __builtin_amdgcn_s_setprio(0);
}

#define BAR()   __builtin_amdgcn_s_barrier()
#define LGKM0() asm volatile("s_waitcnt lgkmcnt(0)" ::: "memory")
#define VMC(n)  asm volatile("s_waitcnt vmcnt(%0)" :: "n"(n) : "memory")

template <int MODE>  // 0 = steady, 1 = final iteration (no t2/t3 stages)
__device__ __forceinline__ void iter8(const ushort_t* __restrict__ A,
                                      const ushort_t* __restrict__ xp,
                                      ushort_t* lds, int m0, int n0, int it,
                                      int wid, int lane, int wr, int wc, int r15, int kh,
                                      f32x4 (&acc)[8][4]) {
    const int t1 = 2 * it + 1, t2 = 2 * it + 2, t3 = 2 * it + 3;
    const ushort_t* d0A = lds;
    const ushort_t* d0B = lds + 16384;
    const ushort_t* d1A = lds + 32768;
    const ushort_t* d1B = lds + 49152;
    ushort_t* w0A = lds;         ushort_t* w0B = lds + 16384;
    ushort_t* w1A = lds + 32768; ushort_t* w1B = lds + 49152;
    bf16x8 af[4][2], bq[4][2];

    // ===== tile t0 (dbuf0) =====
    // ph1: Q(r0,c0) — reads 12; stage B(t1)h1
    rdA(af, d0A, wr * 128, r15, kh);
    rdB(bq, 0, d0B, wc * 64, r15, kh);
    stageB8(w1B + 8192, xp, n0, 1, t1, wid, lane);
    BAR(); LGKM0();
    mfmaQ<0, 0>(acc, af, bq);
    BAR();
    // ph2: Q(r0,c1) — reads 4; stage A(t1)h1
    rdB(bq, 2, d0B, wc * 64 + 32, r15, kh);
    stageA8(w1A + 8192, A, m0, 1, t1, wid, lane);
    BAR(); LGKM0();
    mfmaQ<0, 2>(acc, af, bq);
    BAR();
    // ph3: Q(r1,c0) — reads 8; stage B(t2)h0
    rdA(af, d0A, wr * 128 + 64, r15, kh);
    if (MODE == 0) stageB8(w0B, xp, n0, 0, t2, wid, lane);
    BAR(); LGKM0();
    mfmaQ<4, 0>(acc, af, bq);
    BAR();
    // ph4: Q(r1,c1) — reads 0; stage A(t2)h0; GATE
    if (MODE == 0) { stageA8(w0A, A, m0, 0, t2, wid, lane); VMC(4); }
    else           { VMC(0); }
    BAR();
    mfmaQ<4, 2>(acc, af, bq);
    BAR();
    // ===== tile t1 (dbuf1) =====
    // ph5
    rdA(af, d1A, wr * 128, r15, kh);
    rdB(bq, 0, d1B, wc * 64, r15, kh);
    if (MODE == 0) stageB8(w0B + 8192, xp, n0, 1, t2, wid, lane);
    BAR(); LGKM0();
    mfmaQ<0, 0>(acc, af, bq);
    BAR();
    // ph6
    rdB(bq, 2, d1B, wc * 64 + 32, r15, kh);
    if (MODE == 0) stageA8(w0A + 8192, A, m0, 1, t2, wid, lane);
    BAR(); LGKM0();
    mfmaQ<0, 2>(acc, af, bq);
    BAR();
    // ph7
    rdA(af, d1A, wr * 128 + 64, r15, kh);
    if (MODE == 0) stageB8(w1B, xp, n0, 0, t3, wid, lane);
    BAR(); LGKM0();
    mfmaQ<4, 0>(acc, af, bq);
    BAR();
    // ph8 — GATE
    if (MODE == 0) { stageA8(w1A, A, m0, 0, t3, wid, lane); VMC(4); }
    BAR();
    mfmaQ<4, 2>(acc, af, bq);
    BAR();
}

__global__ __launch_bounds__(512, 1) void gemm256p_off_fused(const ushort_t* __restrict__ A,
                                                             const ushort_t* __restrict__ xp,
                                                             const float* __restrict__ boff,
                                                             const float* __restrict__ x,
                                                             ushort_t* __restrict__ s) {
    __shared__ __align__(16) ushort_t lds[65536];        // 128 KiB (2 dbuf x 64 KB)
    constexpr int NT = NTOT / 256;                        // 64 n-tiles
    constexpr int NWG = (MOFF / 256) * NT;                // 896 (%8==0)
    int bid = blockIdx.x;
    int wg = (bid & 7) * (NWG / 8) + (bid >> 3);          // XCD-bijective swizzle
    int mt = wg / NT, nt = wg % NT;
    int m0 = mt * 256, n0 = nt * 256;
    int tid = threadIdx.x, wid = tid >> 6, lane = tid & 63;
    int wr = wid >> 2, wc = wid & 3;
    int r15 = lane & 15, kh = lane >> 4;

    f32x4 acc[8][4] = {};

    // Prologue: tile0 (4 halves) + tile1 h0 halves; drain to 4 outstanding.
    stageB8(lds + 16384,         xp, n0, 0, 0, wid, lane);   // B0h0
    stageA8(lds,                 A,  m0, 0, 0, wid, lane);   // A0h0
    stageB8(lds + 16384 + 8192,  xp, n0, 1, 0, wid, lane);   // B0h1
    stageA8(lds + 8192,          A,  m0, 1, 0, wid, lane);   // A0h1
    stageB8(lds + 49152,         xp, n0, 0, 1, wid, lane);   // B1h0
    stageA8(lds + 32768,         A,  m0, 0, 1, wid, lane);   // A1h0
    VMC(4);
    BAR();

#pragma unroll 1
    for (int it = 0; it < NITER - 1; ++it)
        iter8<0>(A, xp, lds, m0, n0, it, wid, lane, wr, wc, r15, kh, acc);
    iter8<1>(A, xp, lds, m0, n0, NITER - 1, wid, lane, wr, wc, r15, kh, acc);

    // ---- fused epilogue: bias + sigmoid + deformable lerp -> LDS transpose tile ----
    __syncthreads();                     // K-loop LDS dead
    ushort_t* st = lds;                  // [256 n][136 pitch] bf16 tile (69.6 KB)
#pragma unroll
    for (int i = 0; i < 8; ++i) {
        int mloc = wr * 128 + i * 16 + kh * 4;            // local m (even)
        int ckb  = (m0 + mloc) >> 1;                       // global ck base (2 cks)
        int ckl  = mloc >> 1;                              // local ck (even, 0..126)
        float bo0 = boff[ckb],     bm0 = boff[KD + ckb];
        float bo1 = boff[ckb + 1], bm1 = boff[KD + ckb + 1];
        int c0 = ckb / 7,       kk0 = ckb - c0 * 7;
        int c1 = (ckb + 1) / 7, kk1 = (ckb + 1) - c1 * 7;
#pragma unroll
        for (int j = 0; j < 4; ++j) {
            int nl = wc * 64 + j * 16 + r15;
            int n = n0 + nl;
            int b = n >> 11, l = n & 2047;
            const float* xb_ = x + (size_t)b * (CC * LL);
            f32x4 v = acc[i][j];
            ushort2 o2;
#pragma unroll
            for (int p = 0; p < 2; ++p) {
                float offv = v[2 * p]     + (p ? bo1 : bo0);
                float mpre = v[2 * p + 1] + (p ? bm1 : bm0);
                int c = p ? c1 : c0, kk = p ? kk1 : kk0;
                float mask = 1.0f / (1.0f + __expf(-mpre));
                float pos = offv + (float)(l - PADc + kk);
                float p0f = floorf(pos);
                float frac = pos - p0f;
                int p0 = (int)p0f;
                const float* xr = xb_ + (size_t)c * LL;
                float x0 = ((unsigned)p0 < (unsigned)LL) ? xr[p0] : 0.0f;
                float x1 = ((unsigned)(p0 + 1) < (unsigned)LL) ? xr[p0 + 1] : 0.0f;
                float sv = (x0 + (x1 - x0) * frac) * mask;
                if (p) o2.y = f2bf(sv); else o2.x = f2bf(sv);
            }
            *(ushort2*)(st + nl * 136 + ckl) = o2;         // 2-way banks: free
        }
    }
    __syncthreads();
    int srow = tid >> 5, scol = tid & 31;
    int ck0g = m0 >> 1;
#pragma unroll
    for (int pass = 0; pass < 16; ++pass) {
        int nl = pass * 16 + srow;
        ushort4 v4 = *(const ushort4*)(st + nl * 136 + scol * 4);
        *(ushort4*)(s + (size_t)(n0 + nl) * KD + ck0g + scol * 4) = v4;
    }
}

// ==================== 128x128 counted-vmcnt GEMM (main conv, unchanged) ====================
__device__ __forceinline__ void stage128(ushort_t* ldsbuf,
                                         const ushort_t* __restrict__ A,
                                         const ushort_t* __restrict__ Bt,
                                         int m0, int n0, int kt,
                                         int wid, int lane) {
    int t = wid * 64 + lane;
    int g = (t & 3) ^ ((t >> 3) & 3);
#pragma unroll
    for (int j = 0; j < 2; ++j) {
        int row = j * 64 + (t >> 2);
        load_lds16(A  + (size_t)(m0 + row) * KD + kt * 32 + g * 8,
                   ldsbuf + j * 2048 + wid * 512);
        load_lds16(Bt + (size_t)(n0 + row) * KD + kt * 32 + g * 8,
                   ldsbuf + 4096 + j * 2048 + wid * 512);
    }
}

template <int VMCN>
__device__ __forceinline__ void kstep128(const ushort_t* __restrict__ A,
                                         const ushort_t* __restrict__ Bt,
                                         ushort_t* lds, int m0, int n0, int kt,
                                         int wid, int lane, int wr, int wc,
                                         int r15, int u, f32x4 (&acc)[4][4]) {
    asm volatile("s_waitcnt vmcnt(%0)" :: "n"(VMCN) : "memory");
    __builtin_amdgcn_s_barrier();
    const ushort_t* buf = lds + (size_t)(kt & 3) * 8192;
    const ushort_t* pa = buf + (wr * 64 + r15) * 32 + u * 8;
    const ushort_t* pb = buf + 4096 + (wc * 64 + r15) * 32 + u * 8;
    bf16x8 af[4], bq[4];
#pragma unroll
    for (int i = 0; i < 4; ++i) af[i] = *(const bf16x8*)(pa + i * 512);
#pragma unroll
    for (int j = 0; j < 4; ++j) bq[j] = *(const bf16x8*)(pb + j * 512);
    if (kt + 3 < NKSTEPS)
        stage128(lds + (size_t)((kt + 3) & 3) * 8192, A, Bt, m0, n0, kt + 3, wid, lane);
    __builtin_amdgcn_s_setprio(1);
#pragma unroll
    for (int i = 0; i < 4; ++i)
#pragma unroll
        for (int j = 0; j < 4; ++j)
            acc[i][j] = __builtin_amdgcn_mfma_f32_16x16x32_bf16(af[i], bq[j], acc[i][j], 0, 0, 0);
    __builtin_amdgcn_s_setprio(0);
}

__global__ __launch_bounds__(256, 2) void gemm128_out(const ushort_t* __restrict__ A,
                                                      const ushort_t* __restrict__ Bt,
                                                      const float* __restrict__ bvec,
                                                      float* __restrict__ Dout) {
    __shared__ __align__(16) ushort_t lds[4 * 8192];     // 64 KiB ring
    constexpr int NT = NTOT / 128;
    constexpr int NWG = (OUTC / 128) * NT;                // 256 (%8==0)
    int bid = blockIdx.x;
    int wg = (bid & 7) * (NWG / 8) + (bid >> 3);
    int mt = wg / NT, nt = wg % NT;
    int m0 = mt * 128, n0 = nt * 128;
    int tid = threadIdx.x, wid = tid >> 6, lane = tid & 63;
    int wr = wid >> 1, wc = wid & 1;
    int r15 = lane & 15, kh = lane >> 4;
    int u = kh ^ ((r15 >> 1) & 3);

    f32x4 acc[4][4] = {};

    stage128(lds,            A, Bt, m0, n0, 0, wid, lane);
    stage128(lds + 8192,     A, Bt, m0, n0, 1, wid, lane);
    stage128(lds + 2 * 8192, A, Bt, m0, n0, 2, wid, lane);

    for (int kt = 0; kt < NKSTEPS - 2; ++kt)
        kstep128<8>(A, Bt, lds, m0, n0, kt, wid, lane, wr, wc, r15, u, acc);
    kstep128<4>(A, Bt, lds, m0, n0, NKSTEPS - 2, wid, lane, wr, wc, r15, u, acc);
    kstep128<0>(A, Bt, lds, m0, n0, NKSTEPS - 1, wid, lane, wr, wc, r15, u, acc);

    int rbase = kh * 4;
#pragma unroll
    for (int i = 0; i < 4; ++i)
#pragma unroll
        for (int j = 0; j < 4; ++j) {
            int m = m0 + wr * 64 + i * 16 + rbase;
            int n = n0 + wc * 64 + j * 16 + r15;
            int b = n >> 11, l = n & 2047;
#pragma unroll
            for (int r = 0; r < 4; ++r) {
                float val = acc[i][j][r] + bvec[m + r];
                Dout[((size_t)(b * OUTC + (m + r))) * LL + l] = val;
            }
        }
}

// -------------------- launch --------------------
extern "C" void kernel_launch(void* const* d_in, const int* in_sizes, int n_in,
                              void* d_out, int out_size, void* d_ws, size_t ws_size,
                              hipStream_t stream) {
    const float* x      = (const float*)d_in[0];   // (8,256,2048)
    const float* w_off  = (const float*)d_in[1];   // (3584,256,7)
    const float* b_off  = (const float*)d_in[2];   // (3584,)
    const float* weight = (const float*)d_in[3];   // (256,256,7)
    const float* bias   = (const float*)d_in[4];   // (256,)
    float* out = (float*)d_out;                    // (8,256,2048)

    ushort_t* w = (ushort_t*)d_ws;
    ushort_t* wb  = w;                       // MOFF*KD   = 6,422,528 (c-major/tap-inner, row-permuted)
    ushort_t* wtb = wb  + MOFF * KD;         // OUTC*KD   =   458,752
    ushort_t* xp  = wtb + OUTC * KD;         // BB*LP*256 = 4,206,592 (padded transpose)
    ushort_t* s   = xp  + BB * LP * 256;     // NTOT*KD   = 29,360,128

    castperm_woff<<<(MOFF * KD + 255) / 256, 256, 0, stream>>>(w_off, wb);
    cast_k<<<(114688 + 255) / 256, 256, 0, stream>>>((const float4*)weight, wtb, 114688);
    xpose_k<<<512, 256, 0, stream>>>(x, xp);

    // offset conv (8-phase counted-vmcnt, tap-B c-major) + fused sampling: writes s[n][ck]
    gemm256p_off_fused<<<(MOFF / 256) * (NTOT / 256), 512, 0, stream>>>(wb, xp, b_off, x, s);

    // main conv: [256 x 1792] * [1792 x 16384]
    gemm128_out<<<(OUTC / 128) * (NTOT / 128), 256, 0, stream>>>(wtb, s, bias, out);
}

// Round 11
// 280.189 us; speedup vs baseline: 1.0232x; 1.0232x over previous
//
#include <hip/hip_runtime.h>

typedef unsigned short ushort_t;
typedef __attribute__((ext_vector_type(8))) short bf16x8;
typedef __attribute__((ext_vector_type(4))) float f32x4;
typedef __attribute__((ext_vector_type(8))) unsigned short ushort8;

// Problem geometry (compile-time)
constexpr int BB   = 8;
constexpr int CC   = 256;
constexpr int OUTC = 256;
constexpr int KK   = 7;
constexpr int LL   = 2048;
constexpr int PADc = 3;
constexpr int KD   = CC * KK;        // 1792 reduction dim
constexpr int MOFF = CC * KK * 2;    // 3584 offset-conv out channels
constexpr int NTOT = BB * LL;        // 16384
constexpr int NKSTEPS = KD / 32;     // 56
constexpr int LP   = LL + 6;         // 2054 padded length
constexpr int BUFU = 12288;          // ring buffer (24 KB: A 8K + B 16K) in ushorts

__device__ __forceinline__ ushort_t f2bf(float f) {
    unsigned u = __float_as_uint(f);
    unsigned r = (u + 0x7fffu + ((u >> 16) & 1u)) >> 16;  // RNE
    return (ushort_t)r;
}

// -------------------- cast f32 -> bf16 (vectorized, main-conv weight) --------------------
__global__ __launch_bounds__(256) void cast_k(const float4* __restrict__ src,
                                              ushort_t* __restrict__ dst, int n4) {
    int i = blockIdx.x * 256 + threadIdx.x;
    if (i >= n4) return;
    float4 v = src[i];
    ushort4 o;
    o.x = f2bf(v.x); o.y = f2bf(v.y); o.z = f2bf(v.z); o.w = f2bf(v.w);
    *(ushort4*)(dst + (size_t)i * 4) = o;
}

// ------ cast + permute w_off into c-major/tap-inner K layout ------
// K index q: chunk ks = q>>5 (cs = ks/7, tap = ks%7), cl = q&31 -> (c = cs*32+cl, kk = tap)
__global__ __launch_bounds__(256) void castperm_woff(const float* __restrict__ src,
                                                     ushort_t* __restrict__ dst) {
    int i = blockIdx.x * 256 + threadIdx.x;
    if (i >= MOFF * KD) return;
    int dr  = i / KD;
    int q   = i - dr * KD;
    int cs   = q / 224;
    int r224 = q - cs * 224;
    int tap  = r224 >> 5;
    int cl   = r224 & 31;
    int c = cs * 32 + cl;
    int r = (dr & 1) ? (KD + (dr >> 1)) : (dr >> 1);
    dst[i] = f2bf(src[(r * 256 + c) * 7 + tap]);
}

// -------------------- padded transpose: xp[b][l+3][c] = x[b][c][l] --------------------
__global__ __launch_bounds__(256) void xpose_k(const float* __restrict__ x,
                                               ushort_t* __restrict__ xp) {
    __shared__ float tile[32][257];
    int bid = blockIdx.x;                 // 8 b x 8 ltiles x 8 cchunks = 512
    int b  = bid >> 6;
    int l0 = ((bid >> 3) & 7) * 256;
    int c0 = (bid & 7) * 32;
    int tid = threadIdx.x;
    const float* xb = x + (size_t)b * (CC * LL);
    ushort_t* xpb = xp + (size_t)b * (LP * 256);
#pragma unroll 4
    for (int k = 0; k < 32; ++k)
        tile[k][tid] = xb[(size_t)(c0 + k) * LL + l0 + tid];
    __syncthreads();
    int lp = l0 + tid + 3;
#pragma unroll
    for (int q = 0; q < 8; ++q) {
        ushort4 v;
        v.x = f2bf(tile[4 * q + 0][tid]);
        v.y = f2bf(tile[4 * q + 1][tid]);
        v.z = f2bf(tile[4 * q + 2][tid]);
        v.w = f2bf(tile[4 * q + 3][tid]);
        *(ushort4*)(xpb + (size_t)lp * 256 + c0 + 4 * q) = v;
    }
    if ((bid & 63) == 0) {
#pragma unroll
        for (int r = 0; r < 6; ++r) {
            int glp = (r < 3) ? r : (2048 + r);
            xpb[glp * 256 + tid] = 0;
        }
    }
}

// -------------------- async global->LDS 16B --------------------
__device__ __forceinline__ void load_lds16(const ushort_t* g, ushort_t* l) {
    __builtin_amdgcn_global_load_lds(
        (const __attribute__((address_space(1))) unsigned int*)g,
        (__attribute__((address_space(3))) unsigned int*)l, 16, 0, 0);
}

// ==================== 128x256 register-prefetch GEMM + tap-B (c-major) + fused sampling ====================
// 4 waves (256 thr), per-wave 128x64 (acc[8][4] = 32 MFMA/kstep), ring-3 x 24KB = 72KB
// -> 2 blocks/CU. 2-deep REGISTER pipeline: during kstep kt, after vmcnt(6)+barrier
// (drains oldest 6 = stage(kt+1); the 6 just-issued stage(kt+2) stay in flight),
// issue the 12 ds_reads of frags(kt+1) and run MFMA(kt) on previously-read registers
// -> LDS pipe overlaps the matrix pipe within every wave.
// Hazards: stage(kt+2) overwrites buf(kt-1) two barriers after its last reads retired;
// prefetch(kt+1) follows every wave's vmcnt(6)+B2; compiler inserts exact lgkm waits.
__device__ __forceinline__ void stageAp(ushort_t* ldsbuf, const ushort_t* __restrict__ A,
                                        int m0, int kt, int tid) {
    int g = (tid & 3) ^ ((tid >> 3) & 3);    // pre-swizzled global 16B-slot
    int w = tid >> 6;
#pragma unroll
    for (int j = 0; j < 2; ++j) {
        int row = j * 64 + (tid >> 2);
        load_lds16(A + (size_t)(m0 + row) * KD + kt * 32 + g * 8,
                   ldsbuf + j * 2048 + w * 512);
    }
}
__device__ __forceinline__ void stageBp(ushort_t* ldsbuf, const ushort_t* __restrict__ xp,
                                        int n0, int kt, int tid) {
    int g = (tid & 3) ^ ((tid >> 3) & 3);
    int cs = kt / 7, tap = kt - cs * 7;       // uniform -> SALU
    const ushort_t* base = xp + (size_t)(n0 >> 11) * (LP * 256)
                              + (size_t)((n0 & 2047) + tap) * 256 + cs * 32 + g * 8;
    int w = tid >> 6;
#pragma unroll
    for (int j = 0; j < 4; ++j) {
        int row = j * 64 + (tid >> 2);
        load_lds16(base + (size_t)row * 256, ldsbuf + 4096 + j * 2048 + w * 512);
    }
}

__device__ __forceinline__ void readFrags(const ushort_t* buf, int wc, int r15, int u,
                                          bf16x8 (&af)[8], bf16x8 (&bq)[4]) {
    const ushort_t* pa = buf + r15 * 32 + u * 8;
    const ushort_t* pb = buf + 4096 + (wc * 64 + r15) * 32 + u * 8;
#pragma unroll
    for (int i = 0; i < 8; ++i) af[i] = *(const bf16x8*)(pa + i * 512);
#pragma unroll
    for (int j = 0; j < 4; ++j) bq[j] = *(const bf16x8*)(pb + j * 512);
}

template <int MODE>  // 0 steady; 1 = kt==54 (no stage, vmcnt(0)); 2 = kt==55 (MFMA only)
__device__ __forceinline__ void kstepP(const ushort_t* __restrict__ A,
                                       const ushort_t* __restrict__ xp,
                                       ushort_t* lds, int m0, int n0, int kt,
                                       int tid, int wc, int r15, int u,
                                       bf16x8 (&afC)[8], bf16x8 (&bqC)[4],
                                       bf16x8 (&afP)[8], bf16x8 (&bqP)[4],
                                       f32x4 (&acc)[8][4]) {
    if (MODE != 2) {
        __builtin_amdgcn_s_barrier();                                  // B1
        if (MODE == 0) {
            ushort_t* nb = lds + (size_t)((kt + 2) % 3) * BUFU;
            stageAp(nb, A,  m0, kt + 2, tid);
            stageBp(nb, xp, n0, kt + 2, tid);
            asm volatile("s_waitcnt vmcnt(6)" ::: "memory");           // drain stage(kt+1)
        } else {
            asm volatile("s_waitcnt vmcnt(0)" ::: "memory");
        }
        __builtin_amdgcn_s_barrier();                                  // B2: buf(kt+1) ready
        readFrags(lds + (size_t)((kt + 1) % 3) * BUFU, wc, r15, u, afP, bqP);
    }
    __builtin_amdgcn_s_setprio(1);
#pragma unroll
    for (int i = 0; i < 8; ++i)
#pragma unroll
        for (int j = 0; j < 4; ++j)
            acc[i][j] = __builtin_amdgcn_mfma_f32_16x16x32_bf16(afC[i], bqC[j], acc[i][j], 0, 0, 0);
    __builtin_amdgcn_s_setprio(0);
}

__global__ __launch_bounds__(256, 2) void gemm128p_off_fused(const ushort_t* __restrict__ A,
                                                             const ushort_t* __restrict__ xp,
                                                             const float* __restrict__ boff,
                                                             const float* __restrict__ x,
                                                             ushort_t* __restrict__ s) {
    __shared__ __align__(16) ushort_t lds[3 * BUFU];     // 72 KiB ring -> 2 blocks/CU
    constexpr int NT = NTOT / 256;                        // 64 n-tiles
    constexpr int NWG = (MOFF / 128) * NT;                // 1792 (%8==0)
    int bid = blockIdx.x;
    int wg = (bid & 7) * (NWG / 8) + (bid >> 3);          // XCD-bijective swizzle
    int mt = wg / NT, nt = wg % NT;
    int m0 = mt * 128, n0 = nt * 256;
    int tid = threadIdx.x, lane = tid & 63;
    int wc = tid >> 6;                                    // 4 waves: 1M x 4N
    int r15 = lane & 15, kh = lane >> 4;
    int u = kh ^ ((r15 >> 1) & 3);                        // swizzled read slot

    f32x4 acc[8][4] = {};
    bf16x8 afA[8], bqA[4], afB[8], bqB[4];

    // prologue: stage bufs 0,1; wait buf0; read frags(0) into A-set
    stageAp(lds,        A,  m0, 0, tid);
    stageBp(lds,        xp, n0, 0, tid);
    stageAp(lds + BUFU, A,  m0, 1, tid);
    stageBp(lds + BUFU, xp, n0, 1, tid);
    asm volatile("s_waitcnt vmcnt(6)" ::: "memory");
    __builtin_amdgcn_s_barrier();
    readFrags(lds, wc, r15, u, afA, bqA);

#pragma unroll 1
    for (int p = 0; p < 27; ++p) {
        kstepP<0>(A, xp, lds, m0, n0, 2 * p,     tid, wc, r15, u, afA, bqA, afB, bqB, acc);
        kstepP<0>(A, xp, lds, m0, n0, 2 * p + 1, tid, wc, r15, u, afB, bqB, afA, bqA, acc);
    }
    kstepP<1>(A, xp, lds, m0, n0, 54, tid, wc, r15, u, afA, bqA, afB, bqB, acc);
    kstepP<2>(A, xp, lds, m0, n0, 55, tid, wc, r15, u, afB, bqB, afA, bqA, acc);

    // ---- fused epilogue: bias + sigmoid + deformable lerp -> LDS transpose tile ----
    __syncthreads();                     // K-loop LDS dead
    ushort_t* st = lds;                  // [256 n][72 pitch] bf16 tile (36 KB)
#pragma unroll
    for (int i = 0; i < 8; ++i) {
        int mloc = i * 16 + kh * 4;                       // local m (even), 0..124
        int ckb  = (m0 + mloc) >> 1;                       // global ck base (2 cks)
        int ckl  = mloc >> 1;                              // local ck (even, 0..62)
        float bo0 = boff[ckb],     bm0 = boff[KD + ckb];
        float bo1 = boff[ckb + 1], bm1 = boff[KD + ckb + 1];
        int c0 = ckb / 7,       kk0 = ckb - c0 * 7;
        int c1 = (ckb + 1) / 7, kk1 = (ckb + 1) - c1 * 7;
#pragma unroll
        for (int j = 0; j < 4; ++j) {
            int nl = wc * 64 + j * 16 + r15;
            int n = n0 + nl;
            int b = n >> 11, l = n & 2047;
            const float* xb_ = x + (size_t)b * (CC * LL);
            f32x4 v = acc[i][j];
            ushort2 o2;
#pragma unroll
            for (int p = 0; p < 2; ++p) {
                float offv = v[2 * p]     + (p ? bo1 : bo0);
                float mpre = v[2 * p + 1] + (p ? bm1 : bm0);
                int c = p ? c1 : c0, kk = p ? kk1 : kk0;
                float mask = 1.0f / (1.0f + __expf(-mpre));
                float pos = offv + (float)(l - PADc + kk);
                float p0f = floorf(pos);
                float frac = pos - p0f;
                int p0 = (int)p0f;
                const float* xr = xb_ + (size_t)c * LL;
                float x0 = ((unsigned)p0 < (unsigned)LL) ? xr[p0] : 0.0f;
                float x1 = ((unsigned)(p0 + 1) < (unsigned)LL) ? xr[p0 + 1] : 0.0f;
                float sv = (x0 + (x1 - x0) * frac) * mask;
                if (p) o2.y = f2bf(sv); else o2.x = f2bf(sv);
            }
            *(ushort2*)(st + nl * 72 + ckl) = o2;
        }
    }
    __syncthreads();
    // coalesced store-back: 256 rows x 128B; 8 lanes x ushort8 per row, 8 passes
    int srow = tid >> 3;                 // 0..31
    int scol = tid & 7;                  // 0..7
    int ck0g = m0 >> 1;
#pragma unroll
    for (int pass = 0; pass < 8; ++pass) {
        int nl = pass * 32 + srow;
        ushort8 v8 = *(const ushort8*)(st + nl * 72 + scol * 8);
        *(ushort8*)(s + (size_t)(n0 + nl) * KD + ck0g + scol * 8) = v8;
    }
}

// ==================== 128x128 counted-vmcnt GEMM (main conv, unchanged) ====================
__device__ __forceinline__ void stage128(ushort_t* ldsbuf,
                                         const ushort_t* __restrict__ A,
                                         const ushort_t* __restrict__ Bt,
                                         int m0, int n0, int kt,
                                         int wid, int lane) {
    int t = wid * 64 + lane;
    int g = (t & 3) ^ ((t >> 3) & 3);
#pragma unroll
    for (int j = 0; j < 2; ++j) {
        int row = j * 64 + (t >> 2);
        load_lds16(A  + (size_t)(m0 + row) * KD + kt * 32 + g * 8,
                   ldsbuf + j * 2048 + wid * 512);
        load_lds16(Bt + (size_t)(n0 + row) * KD + kt * 32 + g * 8,
                   ldsbuf + 4096 + j * 2048 + wid * 512);
    }
}

template <int VMCN>
__device__ __forceinline__ void kstep128(const ushort_t* __restrict__ A,
                                         const ushort_t* __restrict__ Bt,
                                         ushort_t* lds, int m0, int n0, int kt,
                                         int wid, int lane, int wr, int wc,
                                         int r15, int u, f32x4 (&acc)[4][4]) {
    asm volatile("s_waitcnt vmcnt(%0)" :: "n"(VMCN) : "memory");
    __builtin_amdgcn_s_barrier();
    const ushort_t* buf = lds + (size_t)(kt & 3) * 8192;
    const ushort_t* pa = buf + (wr * 64 + r15) * 32 + u * 8;
    const ushort_t* pb = buf + 4096 + (wc * 64 + r15) * 32 + u * 8;
    bf16x8 af[4], bq[4];
#pragma unroll
    for (int i = 0; i < 4; ++i) af[i] = *(const bf16x8*)(pa + i * 512);
#pragma unroll
    for (int j = 0; j < 4; ++j) bq[j] = *(const bf16x8*)(pb + j * 512);
    if (kt + 3 < NKSTEPS)
        stage128(lds + (size_t)((kt + 3) & 3) * 8192, A, Bt, m0, n0, kt + 3, wid, lane);
    __builtin_amdgcn_s_setprio(1);
#pragma unroll
    for (int i = 0; i < 4; ++i)
#pragma unroll
        for (int j = 0; j < 4; ++j)
            acc[i][j] = __builtin_amdgcn_mfma_f32_16x16x32_bf16(af[i], bq[j], acc[i][j], 0, 0, 0);
    __builtin_amdgcn_s_setprio(0);
}

__global__ __launch_bounds__(256, 2) void gemm128_out(const ushort_t* __restrict__ A,
                                                      const ushort_t* __restrict__ Bt,
                                                      const float* __restrict__ bvec,
                                                      float* __restrict__ Dout) {
    __shared__ __align__(16) ushort_t lds[4 * 8192];     // 64 KiB ring
    constexpr int NT = NTOT / 128;
    constexpr int NWG = (OUTC / 128) * NT;                // 256 (%8==0)
    int bid = blockIdx.x;
    int wg = (bid & 7) * (NWG / 8) + (bid >> 3);
    int mt = wg / NT, nt = wg % NT;
    int m0 = mt * 128, n0 = nt * 128;
    int tid = threadIdx.x, wid = tid >> 6, lane = tid & 63;
    int wr = wid >> 1, wc = wid & 1;
    int r15 = lane & 15, kh = lane >> 4;
    int u = kh ^ ((r15 >> 1) & 3);

    f32x4 acc[4][4] = {};

    stage128(lds,            A, Bt, m0, n0, 0, wid, lane);
    stage128(lds + 8192,     A, Bt, m0, n0, 1, wid, lane);
    stage128(lds + 2 * 8192, A, Bt, m0, n0, 2, wid, lane);

    for (int kt = 0; kt < NKSTEPS - 2; ++kt)
        kstep128<8>(A, Bt, lds, m0, n0, kt, wid, lane, wr, wc, r15, u, acc);
    kstep128<4>(A, Bt, lds, m0, n0, NKSTEPS - 2, wid, lane, wr, wc, r15, u, acc);
    kstep128<0>(A, Bt, lds, m0, n0, NKSTEPS - 1, wid, lane, wr, wc, r15, u, acc);

    int rbase = kh * 4;
#pragma unroll
    for (int i = 0; i < 4; ++i)
#pragma unroll
        for (int j = 0; j < 4; ++j) {
            int m = m0 + wr * 64 + i * 16 + rbase;
            int n = n0 + wc * 64 + j * 16 + r15;
            int b = n >> 11, l = n & 2047;
#pragma unroll
            for (int r = 0; r < 4; ++r) {
                float val = acc[i][j][r] + bvec[m + r];
                Dout[((size_t)(b * OUTC + (m + r))) * LL + l] = val;
            }
        }
}

// -------------------- launch --------------------
extern "C" void kernel_launch(void* const* d_in, const int* in_sizes, int n_in,
                              void* d_out, int out_size, void* d_ws, size_t ws_size,
                              hipStream_t stream) {
    const float* x      = (const float*)d_in[0];   // (8,256,2048)
    const float* w_off  = (const float*)d_in[1];   // (3584,256,7)
    const float* b_off  = (const float*)d_in[2];   // (3584,)
    const float* weight = (const float*)d_in[3];   // (256,256,7)
    const float* bias   = (const float*)d_in[4];   // (256,)
    float* out = (float*)d_out;                    // (8,256,2048)

    ushort_t* w = (ushort_t*)d_ws;
    ushort_t* wb  = w;                       // MOFF*KD   = 6,422,528 (c-major/tap-inner, row-permuted)
    ushort_t* wtb = wb  + MOFF * KD;         // OUTC*KD   =   458,752
    ushort_t* xp  = wtb + OUTC * KD;         // BB*LP*256 = 4,206,592 (padded transpose)
    ushort_t* s   = xp  + BB * LP * 256;     // NTOT*KD   = 29,360,128

    castperm_woff<<<(MOFF * KD + 255) / 256, 256, 0, stream>>>(w_off, wb);
    cast_k<<<(114688 + 255) / 256, 256, 0, stream>>>((const float4*)weight, wtb, 114688);
    xpose_k<<<512, 256, 0, stream>>>(x, xp);

    // offset conv (register-prefetch pipeline, tap-B c-major) + fused sampling
    gemm128p_off_fused<<<(MOFF / 128) * (NTOT / 256), 256, 0, stream>>>(wb, xp, b_off, x, s);

    // main conv: [256 x 1792] * [1792 x 16384]
    gemm128_out<<<(OUTC / 128) * (NTOT / 128), 256, 0, stream>>>(wtb, s, bias, out);
}